// Round 1
// baseline (325.524 us; speedup 1.0000x reference)
//
#include <hip/hip_runtime.h>
#include <stdint.h>

typedef unsigned short u16;
typedef __attribute__((ext_vector_type(8))) short short8;
typedef __attribute__((ext_vector_type(4))) float f32x4;

#define B_      16
#define L_      1024
#define H_      1024
#define G_      128
#define M_TOT   16368            // B*(L-1)
#define K_TOT   3072
#define OUT_SEG 2095104          // M_TOT*G_
#define KL_IDX  (4*OUT_SEG)

// ws layout
#define WS_WT_OFF    0           // bf16 W'T [512][3072] = 3,145,728 B
#define WS_BIAS_OFF  3145728     // float[512]
#define WS_KL_OFF    3147776     // double

__device__ inline u16 f2bf(float f) {
    union { float f; uint32_t u; } x; x.f = f;
    uint32_t u = x.u;
    return (u16)((u + 0x7fffu + ((u >> 16) & 1u)) >> 16);
}

__device__ inline void gload16(const void* g, void* l) {
    __builtin_amdgcn_global_load_lds(
        (const __attribute__((address_space(1))) void*)g,
        (__attribute__((address_space(3))) void*)l, 16, 0, 0);
}

__device__ inline short8 cvt8(f32x4 x, f32x4 y) {
    union { short8 s; uint32_t u[4]; } r;
    asm("v_cvt_pk_bf16_f32 %0, %1, %2" : "=v"(r.u[0]) : "v"(x[0]), "v"(x[1]));
    asm("v_cvt_pk_bf16_f32 %0, %1, %2" : "=v"(r.u[1]) : "v"(x[2]), "v"(x[3]));
    asm("v_cvt_pk_bf16_f32 %0, %1, %2" : "=v"(r.u[2]) : "v"(y[0]), "v"(y[1]));
    asm("v_cvt_pk_bf16_f32 %0, %1, %2" : "=v"(r.u[3]) : "v"(y[2]), "v"(y[3]));
    return r.s;
}

// ---------------- prep: build W'T (bf16, [512][3072]) + bias[512], zero KL ----
__global__ __launch_bounds__(256) void prep_kernel(
    const float* __restrict__ Wzm, const float* __restrict__ bzm,
    const float* __restrict__ Wzv, const float* __restrict__ bzv,
    const float* __restrict__ Wqm, const float* __restrict__ bqm,
    const float* __restrict__ Wqv, const float* __restrict__ bqv,
    u16* __restrict__ wt, float* __restrict__ bias, double* __restrict__ klacc)
{
    int n = blockIdx.x;                 // 0..511 (output column)
    int tid = threadIdx.x;
    const float* W; const float* bsrc; int g; int kmax;
    if (n < 128)      { W = Wzm; bsrc = bzm; g = n;       kmax = 2048; }
    else if (n < 256) { W = Wzv; bsrc = bzv; g = n - 128; kmax = 2048; }
    else if (n < 384) { W = Wqm; bsrc = bqm; g = n - 256; kmax = 3072; }
    else              { W = Wqv; bsrc = bqv; g = n - 384; kmax = 3072; }
    if (tid == 0) bias[n] = bsrc[g];
    if (n == 0 && tid == 0) *klacc = 0.0;
    #pragma unroll
    for (int i = 0; i < 12; ++i) {
        int k = i * 256 + tid;
        float v = (k < kmax) ? W[(size_t)k * G_ + g] : 0.0f;
        wt[(size_t)n * K_TOT + k] = f2bf(v);
    }
}

// ---------------- GEMM: out[m, 0:512] = ce @ W' + bias ----------------------
// BM=128, BN=128 (= one output group per blockIdx.y), BK=32, 4 waves (2x2 of 64x64)
__global__ __launch_bounds__(256, 2) void gemm_kernel(
    const float* __restrict__ events, const float* __restrict__ contexts,
    const u16* __restrict__ wt, const float* __restrict__ bias,
    float* __restrict__ out)
{
    __shared__ float Af[2][128 * 32];   // A tile fp32 [row][k]
    __shared__ u16   Bs[2][128 * 32];   // B tile bf16 [n][k] (k-contiguous)

    const int tid  = threadIdx.x;
    const int m0   = blockIdx.x * 128;
    const int nb   = blockIdx.y;        // output group 0..3
    const int lane = tid & 63;
    const int w    = tid >> 6;
    const int wm   = (w >> 1) * 64;
    const int wn   = (w & 1) * 64;
    const int lr   = lane & 15;
    const int kb   = (lane >> 4) * 8;

    // Per-thread A staging chunk sources (4 chunks of 16B per tile).
    // Chunk c = it*256+tid -> row r=c>>3, float offset co=(c&7)*4.
    const float* aB0[4]; const float* aB1[4]; const float* aB2[4];
    #pragma unroll
    for (int it = 0; it < 4; ++it) {
        int c = it * 256 + tid;
        int r = c >> 3;
        int co = (c & 7) * 4;
        int m = m0 + r; if (m > M_TOT - 1) m = M_TOT - 1;
        int b = m / 1023;
        int t = m - b * 1023;
        aB0[it] = events   + ((size_t)(b * L_ + t)) * H_ + co;       // k in [0,1024)
        aB1[it] = events   + ((size_t)(b * L_ + t + 1)) * H_ + co;   // k in [1024,2048)
        aB2[it] = contexts + ((size_t)(b * (L_ - 1) + t)) * H_ + co; // k in [2048,3072)
    }
    // B staging: 2 chunks per thread. c = it*256+tid -> n=c>>2, co=(c&3)*8 (u16)
    const u16* bB[2];
    #pragma unroll
    for (int it = 0; it < 2; ++it) {
        int c = it * 256 + tid;
        int nloc = c >> 2;
        int co = (c & 3) * 8;
        bB[it] = wt + (size_t)(nb * 128 + nloc) * K_TOT + co;
    }

    f32x4 acc[4][4];
    #pragma unroll
    for (int i = 0; i < 4; ++i)
        #pragma unroll
        for (int j = 0; j < 4; ++j)
            acc[i][j] = (f32x4){0.f, 0.f, 0.f, 0.f};

    auto stage = [&](int buf, int kt) {
        int k0 = kt * 32;
        int rg = k0 >> 10;       // source region (tiles never straddle regions)
        int kq = k0 & 1023;
        #pragma unroll
        for (int it = 0; it < 4; ++it) {
            const float* s = (rg == 0) ? aB0[it] : (rg == 1 ? aB1[it] : aB2[it]);
            gload16(s + kq, &Af[buf][(it * 256 + tid) * 4]);
        }
        #pragma unroll
        for (int it = 0; it < 2; ++it) {
            gload16(bB[it] + k0, &Bs[buf][(it * 256 + tid) * 8]);
        }
    };

    auto compute = [&](int buf) {
        const float* Ab = &Af[buf][0];
        const u16*   Bb = &Bs[buf][0];
        short8 a[4]; short8 bfr[4];
        #pragma unroll
        for (int i = 0; i < 4; ++i) {
            const float* p = Ab + (wm + i * 16 + lr) * 32 + kb;
            f32x4 x = *(const f32x4*)p;
            f32x4 y = *(const f32x4*)(p + 4);
            a[i] = cvt8(x, y);
        }
        #pragma unroll
        for (int j = 0; j < 4; ++j)
            bfr[j] = *(const short8*)(Bb + (wn + j * 16 + lr) * 32 + kb);
        #pragma unroll
        for (int i = 0; i < 4; ++i)
            #pragma unroll
            for (int j = 0; j < 4; ++j)
                acc[i][j] = __builtin_amdgcn_mfma_f32_16x16x32_bf16(
                    a[i], bfr[j], acc[i][j], 0, 0, 0);
    };

    stage(0, 0);
    __syncthreads();
    int cur = 0;
    for (int kt = 0; kt < 96; ++kt) {
        if (kt + 1 < 96) stage(cur ^ 1, kt + 1);
        compute(cur);
        __syncthreads();
        cur ^= 1;
    }

    // epilogue: C row = wm + i*16 + (lane>>4)*4 + r ; col = wn + j*16 + (lane&15)
    const float* bptr = bias + nb * 128;
    float* obase = out + (size_t)nb * OUT_SEG;
    #pragma unroll
    for (int i = 0; i < 4; ++i) {
        int mloc = wm + i * 16 + (lane >> 4) * 4;
        #pragma unroll
        for (int j = 0; j < 4; ++j) {
            int g = wn + j * 16 + lr;
            float bv = bptr[g];
            #pragma unroll
            for (int r = 0; r < 4; ++r) {
                int m = m0 + mloc + r;
                if (m < M_TOT) obase[(size_t)m * G_ + g] = acc[i][j][r] + bv;
            }
        }
    }
}

// ---------------- KL reduction ------------------------------------------------
__global__ __launch_bounds__(256) void kl_kernel(const float* __restrict__ out,
                                                 double* __restrict__ klacc)
{
    int row  = blockIdx.x * 4 + (threadIdx.x >> 6);
    int lane = threadIdx.x & 63;
    if (row >= M_TOT) return;
    const float* zm  = out;
    const float* zlv = out + OUT_SEG;
    const float* qm  = out + (size_t)2 * OUT_SEG;
    const float* qlv = out + (size_t)3 * OUT_SEG;
    size_t base = (size_t)row * G_;
    float s = 0.f;
    #pragma unroll
    for (int h = 0; h < 2; ++h) {
        int g = lane + h * 64;
        float a = zm[base + g], b = zlv[base + g];
        float c = qm[base + g], d = qlv[base + g];
        float diff = a - c;
        s += d - b + (__expf(b) + diff * diff) * __expf(-d) - 1.0f;
    }
    #pragma unroll
    for (int off = 32; off > 0; off >>= 1)
        s += __shfl_down(s, off);
    if (lane == 0) atomicAdd(klacc, (double)s);
}

__global__ void kl_final(const double* __restrict__ klacc, float* __restrict__ out)
{
    out[KL_IDX] = (float)(0.5 * (*klacc) / (double)M_TOT);
}

// ---------------- launcher ----------------------------------------------------
extern "C" void kernel_launch(void* const* d_in, const int* in_sizes, int n_in,
                              void* d_out, int out_size, void* d_ws, size_t ws_size,
                              hipStream_t stream)
{
    const float* events   = (const float*)d_in[0];
    const float* contexts = (const float*)d_in[1];
    const float* Wzm = (const float*)d_in[2];
    const float* bzm = (const float*)d_in[3];
    const float* Wzv = (const float*)d_in[4];
    const float* bzv = (const float*)d_in[5];
    const float* Wqm = (const float*)d_in[6];
    const float* bqm = (const float*)d_in[7];
    const float* Wqv = (const float*)d_in[8];
    const float* bqv = (const float*)d_in[9];
    float* out = (float*)d_out;

    u16*    wt    = (u16*)((char*)d_ws + WS_WT_OFF);
    float*  bias  = (float*)((char*)d_ws + WS_BIAS_OFF);
    double* klacc = (double*)((char*)d_ws + WS_KL_OFF);

    prep_kernel<<<512, 256, 0, stream>>>(Wzm, bzm, Wzv, bzv, Wqm, bqm, Wqv, bqv,
                                         wt, bias, klacc);
    dim3 grid(128, 4);
    gemm_kernel<<<grid, 256, 0, stream>>>(events, contexts, wt, bias, out);
    kl_kernel<<<4092, 256, 0, stream>>>(out, klacc);
    kl_final<<<1, 1, 0, stream>>>(klacc, out);
}

// Round 2
// 134.796 us; speedup vs baseline: 2.4149x; 2.4149x over previous
//
#include <hip/hip_runtime.h>
#include <stdint.h>

typedef unsigned short u16;
typedef __attribute__((ext_vector_type(8))) short short8;
typedef __attribute__((ext_vector_type(4))) float f32x4;

#define B_      16
#define L_      1024
#define H_      1024
#define G_      128
#define M_TOT   16368            // B*(L-1)
#define K_TOT   3072
#define OUT_SEG 2095104          // M_TOT*G_
#define KL_IDX  (4*OUT_SEG)
#define KL_BLOCKS 4092           // M_TOT / 4 exactly

// ws layout
#define WS_WT_OFF    0           // bf16 W'T [512][3072] = 3,145,728 B
#define WS_BIAS_OFF  3145728     // float[512]
#define WS_PART_OFF  3147776     // float[4092] block partials

__device__ inline u16 f2bf(float f) {
    union { float f; uint32_t u; } x; x.f = f;
    uint32_t u = x.u;
    return (u16)((u + 0x7fffu + ((u >> 16) & 1u)) >> 16);
}

__device__ inline void gload16(const void* g, void* l) {
    __builtin_amdgcn_global_load_lds(
        (const __attribute__((address_space(1))) void*)g,
        (__attribute__((address_space(3))) void*)l, 16, 0, 0);
}

__device__ inline short8 cvt8(f32x4 x, f32x4 y) {
    union { short8 s; uint32_t u[4]; } r;
    asm("v_cvt_pk_bf16_f32 %0, %1, %2" : "=v"(r.u[0]) : "v"(x[0]), "v"(x[1]));
    asm("v_cvt_pk_bf16_f32 %0, %1, %2" : "=v"(r.u[1]) : "v"(x[2]), "v"(x[3]));
    asm("v_cvt_pk_bf16_f32 %0, %1, %2" : "=v"(r.u[2]) : "v"(y[0]), "v"(y[1]));
    asm("v_cvt_pk_bf16_f32 %0, %1, %2" : "=v"(r.u[3]) : "v"(y[2]), "v"(y[3]));
    return r.s;
}

// ---------------- prep: build W'T (bf16, [512][3072]) + bias[512] ------------
__global__ __launch_bounds__(256) void prep_kernel(
    const float* __restrict__ Wzm, const float* __restrict__ bzm,
    const float* __restrict__ Wzv, const float* __restrict__ bzv,
    const float* __restrict__ Wqm, const float* __restrict__ bqm,
    const float* __restrict__ Wqv, const float* __restrict__ bqv,
    u16* __restrict__ wt, float* __restrict__ bias)
{
    int n = blockIdx.x;                 // 0..511 (output column)
    int tid = threadIdx.x;
    const float* W; const float* bsrc; int g; int kmax;
    if (n < 128)      { W = Wzm; bsrc = bzm; g = n;       kmax = 2048; }
    else if (n < 256) { W = Wzv; bsrc = bzv; g = n - 128; kmax = 2048; }
    else if (n < 384) { W = Wqm; bsrc = bqm; g = n - 256; kmax = 3072; }
    else              { W = Wqv; bsrc = bqv; g = n - 384; kmax = 3072; }
    if (tid == 0) bias[n] = bsrc[g];
    #pragma unroll
    for (int i = 0; i < 12; ++i) {
        int k = i * 256 + tid;
        float v = (k < kmax) ? W[(size_t)k * G_ + g] : 0.0f;
        wt[(size_t)n * K_TOT + k] = f2bf(v);
    }
}

// ---------------- GEMM: out[m, 0:512] = ce @ W' + bias ----------------------
// BM=128, BN=128 (= one output group per blockIdx.y), BK=32, 4 waves (2x2 of 64x64)
__global__ __launch_bounds__(256, 2) void gemm_kernel(
    const float* __restrict__ events, const float* __restrict__ contexts,
    const u16* __restrict__ wt, const float* __restrict__ bias,
    float* __restrict__ out)
{
    __shared__ float Af[2][128 * 32];   // A tile fp32 [row][k]
    __shared__ u16   Bs[2][128 * 32];   // B tile bf16 [n][k] (k-contiguous)

    const int tid  = threadIdx.x;
    const int m0   = blockIdx.x * 128;
    const int nb   = blockIdx.y;        // output group 0..3
    const int lane = tid & 63;
    const int w    = tid >> 6;
    const int wm   = (w >> 1) * 64;
    const int wn   = (w & 1) * 64;
    const int lr   = lane & 15;
    const int kb   = (lane >> 4) * 8;

    // Per-thread A staging chunk sources (4 chunks of 16B per tile).
    const float* aB0[4]; const float* aB1[4]; const float* aB2[4];
    #pragma unroll
    for (int it = 0; it < 4; ++it) {
        int c = it * 256 + tid;
        int r = c >> 3;
        int co = (c & 7) * 4;
        int m = m0 + r; if (m > M_TOT - 1) m = M_TOT - 1;
        int b = m / 1023;
        int t = m - b * 1023;
        aB0[it] = events   + ((size_t)(b * L_ + t)) * H_ + co;       // k in [0,1024)
        aB1[it] = events   + ((size_t)(b * L_ + t + 1)) * H_ + co;   // k in [1024,2048)
        aB2[it] = contexts + ((size_t)(b * (L_ - 1) + t)) * H_ + co; // k in [2048,3072)
    }
    const u16* bB[2];
    #pragma unroll
    for (int it = 0; it < 2; ++it) {
        int c = it * 256 + tid;
        int nloc = c >> 2;
        int co = (c & 3) * 8;
        bB[it] = wt + (size_t)(nb * 128 + nloc) * K_TOT + co;
    }

    f32x4 acc[4][4];
    #pragma unroll
    for (int i = 0; i < 4; ++i)
        #pragma unroll
        for (int j = 0; j < 4; ++j)
            acc[i][j] = (f32x4){0.f, 0.f, 0.f, 0.f};

    auto stage = [&](int buf, int kt) {
        int k0 = kt * 32;
        int rg = k0 >> 10;       // source region (tiles never straddle regions)
        int kq = k0 & 1023;
        #pragma unroll
        for (int it = 0; it < 4; ++it) {
            const float* s = (rg == 0) ? aB0[it] : (rg == 1 ? aB1[it] : aB2[it]);
            gload16(s + kq, &Af[buf][(it * 256 + tid) * 4]);
        }
        #pragma unroll
        for (int it = 0; it < 2; ++it) {
            gload16(bB[it] + k0, &Bs[buf][(it * 256 + tid) * 8]);
        }
    };

    auto compute = [&](int buf) {
        const float* Ab = &Af[buf][0];
        const u16*   Bb = &Bs[buf][0];
        short8 a[4]; short8 bfr[4];
        #pragma unroll
        for (int i = 0; i < 4; ++i) {
            const float* p = Ab + (wm + i * 16 + lr) * 32 + kb;
            f32x4 x = *(const f32x4*)p;
            f32x4 y = *(const f32x4*)(p + 4);
            a[i] = cvt8(x, y);
        }
        #pragma unroll
        for (int j = 0; j < 4; ++j)
            bfr[j] = *(const short8*)(Bb + (wn + j * 16 + lr) * 32 + kb);
        #pragma unroll
        for (int i = 0; i < 4; ++i)
            #pragma unroll
            for (int j = 0; j < 4; ++j)
                acc[i][j] = __builtin_amdgcn_mfma_f32_16x16x32_bf16(
                    a[i], bfr[j], acc[i][j], 0, 0, 0);
    };

    stage(0, 0);
    __syncthreads();
    int cur = 0;
    for (int kt = 0; kt < 96; ++kt) {
        if (kt + 1 < 96) stage(cur ^ 1, kt + 1);
        compute(cur);
        __syncthreads();
        cur ^= 1;
    }

    // epilogue: C row = wm + i*16 + (lane>>4)*4 + r ; col = wn + j*16 + (lane&15)
    const float* bptr = bias + nb * 128;
    float* obase = out + (size_t)nb * OUT_SEG;
    #pragma unroll
    for (int i = 0; i < 4; ++i) {
        int mloc = wm + i * 16 + (lane >> 4) * 4;
        #pragma unroll
        for (int j = 0; j < 4; ++j) {
            int g = wn + j * 16 + lr;
            float bv = bptr[g];
            #pragma unroll
            for (int r = 0; r < 4; ++r) {
                int m = m0 + mloc + r;
                if (m < M_TOT) obase[(size_t)m * G_ + g] = acc[i][j][r] + bv;
            }
        }
    }
}

// ---------------- KL reduction: stage 1 (per-block partials, no atomics) -----
__global__ __launch_bounds__(256) void kl_kernel(const float* __restrict__ out,
                                                 float* __restrict__ partial)
{
    int wid  = threadIdx.x >> 6;
    int row  = blockIdx.x * 4 + wid;        // M_TOT = 4092*4 exactly
    int lane = threadIdx.x & 63;
    const float* zm  = out;
    const float* zlv = out + OUT_SEG;
    const float* qm  = out + (size_t)2 * OUT_SEG;
    const float* qlv = out + (size_t)3 * OUT_SEG;
    size_t base = (size_t)row * G_;
    float s = 0.f;
    #pragma unroll
    for (int h = 0; h < 2; ++h) {
        int g = lane + h * 64;
        float a = zm[base + g], b = zlv[base + g];
        float c = qm[base + g], d = qlv[base + g];
        float diff = a - c;
        s += d - b + (__expf(b) + diff * diff) * __expf(-d) - 1.0f;
    }
    #pragma unroll
    for (int off = 32; off > 0; off >>= 1)
        s += __shfl_down(s, off);
    __shared__ float pw[4];
    if (lane == 0) pw[wid] = s;
    __syncthreads();
    if (threadIdx.x == 0)
        partial[blockIdx.x] = pw[0] + pw[1] + pw[2] + pw[3];
}

// ---------------- KL reduction: stage 2 --------------------------------------
__global__ __launch_bounds__(256) void kl_final(const float* __restrict__ partial,
                                                float* __restrict__ out)
{
    float s = 0.f;
    for (int i = threadIdx.x; i < KL_BLOCKS; i += 256) s += partial[i];
    #pragma unroll
    for (int off = 32; off > 0; off >>= 1)
        s += __shfl_down(s, off);
    __shared__ float pw[4];
    int wid = threadIdx.x >> 6;
    int lane = threadIdx.x & 63;
    if (lane == 0) pw[wid] = s;
    __syncthreads();
    if (threadIdx.x == 0)
        out[KL_IDX] = 0.5f * (pw[0] + pw[1] + pw[2] + pw[3]) / (float)M_TOT;
}

// ---------------- launcher ----------------------------------------------------
extern "C" void kernel_launch(void* const* d_in, const int* in_sizes, int n_in,
                              void* d_out, int out_size, void* d_ws, size_t ws_size,
                              hipStream_t stream)
{
    const float* events   = (const float*)d_in[0];
    const float* contexts = (const float*)d_in[1];
    const float* Wzm = (const float*)d_in[2];
    const float* bzm = (const float*)d_in[3];
    const float* Wzv = (const float*)d_in[4];
    const float* bzv = (const float*)d_in[5];
    const float* Wqm = (const float*)d_in[6];
    const float* bqm = (const float*)d_in[7];
    const float* Wqv = (const float*)d_in[8];
    const float* bqv = (const float*)d_in[9];
    float* out = (float*)d_out;

    u16*   wt      = (u16*)((char*)d_ws + WS_WT_OFF);
    float* bias    = (float*)((char*)d_ws + WS_BIAS_OFF);
    float* partial = (float*)((char*)d_ws + WS_PART_OFF);

    prep_kernel<<<512, 256, 0, stream>>>(Wzm, bzm, Wzv, bzv, Wqm, bqm, Wqv, bqv,
                                         wt, bias);
    dim3 grid(128, 4);
    gemm_kernel<<<grid, 256, 0, stream>>>(events, contexts, wt, bias, out);
    kl_kernel<<<KL_BLOCKS, 256, 0, stream>>>(out, partial);
    kl_final<<<1, 256, 0, stream>>>(partial, out);
}